// Round 1
// baseline (229.297 us; speedup 1.0000x reference)
//
#include <hip/hip_runtime.h>
#include <math.h>

#define NUM_MOVABLE 1000000
#define NUM_FILLER  200000
#define NUM_NODES   1200000
#define NBX 512
#define NBY 512

static constexpr float BSX = 1000.0f / 512.0f;   // bin size, exact (1.953125)
static constexpr float TOTAL_PLACE_AREA = 1000000.0f;
static constexpr float TOTAL_WHITESPACE = 500000.0f;
static constexpr float AREA_STOP  = 0.01f;
static constexpr float ROUTE_STOP = 0.01f;
static constexpr float PIN_STOP   = 0.05f;

// ---------------------------------------------------------------- map prep
__global__ void map_kernel(const float* __restrict__ route,
                           const float* __restrict__ pin,
                           float* __restrict__ rc, float* __restrict__ pc) {
    int i = blockIdx.x * blockDim.x + threadIdx.x;
    if (i >= NBX * NBY) return;
    float r = powf(route[i], 2.5f);
    rc[i] = fminf(fmaxf(r, 0.5f), 2.0f);
    pc[i] = fminf(fmaxf(pin[i], (float)(1.0 / 2.5)), 2.5f);
}

// --------------------------------------------------------------- reduction
__device__ __forceinline__ void block_reduce_atomic4(float v0, float v1,
                                                     float v2, float v3,
                                                     float* acc) {
    __shared__ float lds[8][4];
    #pragma unroll
    for (int o = 32; o >= 1; o >>= 1) {
        v0 += __shfl_down(v0, o, 64);
        v1 += __shfl_down(v1, o, 64);
        v2 += __shfl_down(v2, o, 64);
        v3 += __shfl_down(v3, o, 64);
    }
    int wid = threadIdx.x >> 6, lid = threadIdx.x & 63;
    if (lid == 0) { lds[wid][0] = v0; lds[wid][1] = v1; lds[wid][2] = v2; lds[wid][3] = v3; }
    __syncthreads();
    if (threadIdx.x == 0) {
        float s0 = 0.f, s1 = 0.f, s2 = 0.f, s3 = 0.f;
        int nw = blockDim.x >> 6;
        for (int w = 0; w < nw; ++w) { s0 += lds[w][0]; s1 += lds[w][1]; s2 += lds[w][2]; s3 += lds[w][3]; }
        atomicAdd(&acc[0], s0); atomicAdd(&acc[1], s1);
        atomicAdd(&acc[2], s2); atomicAdd(&acc[3], s3);
    }
}

// ------------------------------------------------------------ bin overlaps
__device__ __forceinline__ void overlaps(float p, float s,
                                         float o[3], int bc[3]) {
    float hi = p + s;
    int b0 = (int)floorf(p / BSX);
    #pragma unroll
    for (int k = 0; k < 3; ++k) {
        int b = b0 + k;
        int c = min(max(b, 0), NBX - 1);
        float bl = (float)c * BSX;
        float v = fminf(hi, bl + BSX) - fmaxf(p, bl);
        v = fmaxf(v, 0.0f);
        o[k] = (b >= 0 && b < NBX) ? v : 0.0f;
        bc[k] = c;
    }
}

// ------------------------------------------------- pass 1: movable gathers
__global__ void pass1_kernel(const float* __restrict__ pos,
                             const float* __restrict__ nsx,
                             const float* __restrict__ nsy,
                             const float* __restrict__ rc,
                             const float* __restrict__ pc,
                             float* __restrict__ inc, float* acc) {
    float s_old = 0.f, s_inc = 0.f, s_r = 0.f, s_p = 0.f;
    for (int i = blockIdx.x * blockDim.x + threadIdx.x; i < NUM_MOVABLE;
         i += gridDim.x * blockDim.x) {
        float px = pos[i], py = pos[NUM_NODES + i];
        float sx = nsx[i], sy = nsy[i];
        float ox[3], oy[3]; int bx[3], by[3];
        overlaps(px, sx, ox, bx);
        overlaps(py, sy, oy, by);
        float r = 0.f, p = 0.f;
        #pragma unroll
        for (int k = 0; k < 3; ++k) {
            #pragma unroll
            for (int l = 0; l < 3; ++l) {
                int idx = bx[k] * NBY + by[l];
                float w = ox[k] * oy[l];
                r += w * rc[idx];
                p += w * pc[idx];
            }
        }
        float old_a = sx * sy;
        float ai = fmaxf(fmaxf(r, p) - old_a, 0.0f);
        inc[i] = ai;
        s_old += old_a;
        s_inc += ai;
        s_r += fmaxf(r - old_a, 0.0f);
        s_p += fmaxf(p - old_a, 0.0f);
    }
    block_reduce_atomic4(s_old, s_inc, s_r, s_p, acc);
}

// ------------------------------------------------------ filler area reduce
__global__ void filler_kernel(const float* __restrict__ nsx,
                              const float* __restrict__ nsy, float* acc) {
    float s = 0.f;
    for (int i = NUM_MOVABLE + blockIdx.x * blockDim.x + threadIdx.x;
         i < NUM_NODES; i += gridDim.x * blockDim.x) {
        s += nsx[i] * nsy[i];
    }
    block_reduce_atomic4(s, 0.f, 0.f, 0.f, acc + 4);
}

// ----------------------------------------------------------- scalar logic
__global__ void scalars_kernel(const float* __restrict__ acc,
                               float* __restrict__ der) {
    if (threadIdx.x != 0 || blockIdx.x != 0) return;
    float old_sum = acc[0], inc_sum = acc[1];
    float route_ex = acc[2], pin_ex = acc[3], filler_sum = acc[4];
    float budget = fminf(0.1f * TOTAL_WHITESPACE, TOTAL_PLACE_AREA - old_sum);
    float raw = budget / inc_sum;
    float scale = fminf(fmaxf(raw, 0.0f), 1.0f);
    float scale_eff = (raw <= 0.0f) ? 0.0f : scale;
    float inc_eff = (raw <= 0.0f) ? 0.0f : inc_sum * scale;
    float new_sum = old_sum + inc_eff;
    float area_ratio = inc_eff / old_sum;
    bool route_flag = (route_ex / old_sum) > ROUTE_STOP;
    bool pin_flag = (pin_ex / old_sum) > PIN_STOP;
    bool adjust = (area_ratio > AREA_STOP) && (route_flag || pin_flag);
    bool fcond = adjust && (new_sum + filler_sum > TOTAL_PLACE_AREA);
    float fratio = sqrtf(fmaxf(TOTAL_PLACE_AREA - new_sum, 0.0f) / filler_sum);
    der[0] = adjust ? 1.0f : 0.0f;
    der[1] = scale_eff;
    der[2] = fcond ? 1.0f : 0.0f;
    der[3] = fratio;
}

// --------------------------------------------------------- pass 3: apply
__global__ void apply_kernel(const float* __restrict__ pos,
                             const float* __restrict__ nsx,
                             const float* __restrict__ nsy,
                             const float* __restrict__ inc,
                             const float* __restrict__ der,
                             float* __restrict__ out) {
    int i = blockIdx.x * blockDim.x + threadIdx.x;
    if (i >= NUM_NODES) return;
    float adjust = der[0], scale_eff = der[1], fcond = der[2], fratio = der[3];
    float px = pos[i], py = pos[NUM_NODES + i];
    float sx = nsx[i], sy = nsy[i];
    float nx = sx, ny = sy, opx = px, opy = py;
    if (i < NUM_MOVABLE) {
        if (adjust > 0.5f) {
            float old_a = sx * sy;
            float na = old_a + inc[i] * scale_eff;
            float mr = sqrtf(na / old_a);
            nx = sx * mr; ny = sy * mr;
            opx = px + 0.5f * (sx - nx);
            opy = py + 0.5f * (sy - ny);
        }
    } else {
        if (fcond > 0.5f) {
            nx = sx * fratio; ny = sy * fratio;
            opx = px + 0.5f * (sx - nx);
            opy = py + 0.5f * (sy - ny);
        }
    }
    out[i] = opx;                      // new_pos x: movable then filler
    out[NUM_NODES + i] = opy;          // new_pos y
    out[2 * NUM_NODES + i] = nx;       // new_nsx
    out[3 * NUM_NODES + i] = ny;       // new_nsy
}

// ---------------------------------------------------------------- launch
extern "C" void kernel_launch(void* const* d_in, const int* in_sizes, int n_in,
                              void* d_out, int out_size, void* d_ws, size_t ws_size,
                              hipStream_t stream) {
    const float* pos       = (const float*)d_in[0];
    const float* node_sx   = (const float*)d_in[1];
    const float* node_sy   = (const float*)d_in[2];
    // d_in[3] pin_offset_x, d_in[4] pin_offset_y, d_in[5] target_density: unused
    const float* route_map = (const float*)d_in[6];
    const float* pin_map   = (const float*)d_in[7];
    float* out = (float*)d_out;

    float* ws  = (float*)d_ws;
    float* rc  = ws;                       // 262144 clamped route map
    float* pc  = rc + NBX * NBY;           // 262144 clamped pin map
    float* inc = pc + NBX * NBY;           // 1e6 per-node area_increment
    float* acc = inc + NUM_MOVABLE;        // 8 accumulators (must be zeroed)
    float* der = acc + 8;                  // 4 derived scalars

    hipMemsetAsync(acc, 0, 8 * sizeof(float), stream);
    hipLaunchKernelGGL(map_kernel, dim3((NBX * NBY + 255) / 256), dim3(256), 0, stream,
                       route_map, pin_map, rc, pc);
    hipLaunchKernelGGL(pass1_kernel, dim3(2048), dim3(256), 0, stream,
                       pos, node_sx, node_sy, rc, pc, inc, acc);
    hipLaunchKernelGGL(filler_kernel, dim3(256), dim3(256), 0, stream,
                       node_sx, node_sy, acc);
    hipLaunchKernelGGL(scalars_kernel, dim3(1), dim3(64), 0, stream, acc, der);
    hipLaunchKernelGGL(apply_kernel, dim3((NUM_NODES + 255) / 256), dim3(256), 0, stream,
                       pos, node_sx, node_sy, inc, der, out);
}